// Round 1
// baseline (707.649 us; speedup 1.0000x reference)
//
#include <hip/hip_runtime.h>
#include <hip/hip_bf16.h>

typedef __bf16 bf16_t;
typedef bf16_t bf16x8 __attribute__((ext_vector_type(8)));
typedef float f32x4 __attribute__((ext_vector_type(4)));

#define PKA 40   // padded LDS k-stride (32 + 8) in bf16 elems

// ---------------------------------------------------------------------------
// K0: Wg1 [k][e] fp32  ->  Wg1T [e][k] bf16  (32x32 LDS tile transpose)
// ---------------------------------------------------------------------------
__global__ void k_wg1t(const float* __restrict__ Wg1, bf16_t* __restrict__ Wg1T) {
    __shared__ float tile[32][33];
    const int k0 = blockIdx.x * 32;
    const int e0 = blockIdx.y * 32;
    const int tx = threadIdx.x;   // 0..31
    const int ty = threadIdx.y;   // 0..7
    #pragma unroll
    for (int i = 0; i < 32; i += 8)
        tile[ty + i][tx] = Wg1[(k0 + ty + i) * 512 + e0 + tx];
    __syncthreads();
    #pragma unroll
    for (int i = 0; i < 32; i += 8)
        Wg1T[(e0 + ty + i) * 512 + k0 + tx] = (bf16_t)tile[tx][ty + i];
}

// ---------------------------------------------------------------------------
// K1: g[b][e] = C_target[b,:] @ Wg2[:,e] + bias[e]   (fp32, one block per b)
// ---------------------------------------------------------------------------
__global__ __launch_bounds__(256) void k_gate(const float* __restrict__ Ct,
                                              const float* __restrict__ Wg2,
                                              const float* __restrict__ bias,
                                              float* __restrict__ g) {
    __shared__ float q[512];
    const int b = blockIdx.x;
    const int t = threadIdx.x;
    q[t]       = Ct[b * 512 + t];
    q[t + 256] = Ct[b * 512 + t + 256];
    __syncthreads();
    #pragma unroll
    for (int eo = 0; eo < 512; eo += 256) {
        const int e = eo + t;
        float acc = bias[e];
        #pragma unroll 8
        for (int k = 0; k < 512; ++k)
            acc += q[k] * Wg2[k * 512 + e];
        g[b * 512 + e] = acc;
    }
}

// ---------------------------------------------------------------------------
// K2: the big GEMM + fused relu/w0 reduction epilogue.
//   score[r] = sum_e relu( (C[r,:] @ Wg1)[e] + g[b,e] ) * w0[e],  masked.
// Block: 256 thr / 4 waves. Tile M=64 x N=512(full), K chunks of 32.
// Wave tile 64x128: 4 m-tiles x 8 n-tiles of 16x16x32 bf16 MFMA.
// ---------------------------------------------------------------------------
__global__ __launch_bounds__(256, 2) void k_score(const float* __restrict__ C,
                                                  const bf16_t* __restrict__ Wg1T,
                                                  const float* __restrict__ g,
                                                  const float* __restrict__ Wg0,
                                                  const int* __restrict__ mask,
                                                  float* __restrict__ score) {
    __shared__ bf16_t As[64 * PKA];     //  5.0 KB
    __shared__ bf16_t Bs[512 * PKA];    // 40.0 KB
    __shared__ float  sred[4][64];      //  1.0 KB

    const int t    = threadIdx.x;
    const int lane = t & 63;
    const int wave = t >> 6;
    const int quad = lane >> 4;
    const int l15  = lane & 15;
    const int row0 = blockIdx.x * 64;   // 2048 blocks
    const int b    = row0 >> 9;         // 64 | 512, so one batch per block

    f32x4 acc[4][8] = {};               // [mi][ni]

    for (int kc = 0; kc < 512; kc += 32) {
        __syncthreads();
        // ---- stage A: 64 rows x 32 k, fp32 -> bf16 ----
        #pragma unroll
        for (int i = 0; i < 2; ++i) {
            const int f  = i * 256 + t;        // 0..511 float4 slots
            const int r  = f >> 3;
            const int c4 = (f & 7) << 2;
            const float4 v = *reinterpret_cast<const float4*>(
                &C[(size_t)(row0 + r) * 512 + kc + c4]);
            union { bf16_t h[4]; uint2 u; } pk;
            pk.h[0] = (bf16_t)v.x; pk.h[1] = (bf16_t)v.y;
            pk.h[2] = (bf16_t)v.z; pk.h[3] = (bf16_t)v.w;
            *reinterpret_cast<uint2*>(&As[r * PKA + c4]) = pk.u;
        }
        // ---- stage B: all 512 n x 32 k of Wg1T (bf16, 16B loads) ----
        #pragma unroll
        for (int i = 0; i < 8; ++i) {
            const int f  = i * 256 + t;        // 0..2047 8-elem slots
            const int r  = f >> 2;
            const int c8 = (f & 3) << 3;
            const uint4 v = *reinterpret_cast<const uint4*>(&Wg1T[r * 512 + kc + c8]);
            *reinterpret_cast<uint4*>(&Bs[r * PKA + c8]) = v;
        }
        __syncthreads();
        // ---- fragments + 32 MFMA ----
        bf16x8 afr[4], bfr[8];
        #pragma unroll
        for (int mi = 0; mi < 4; ++mi)
            afr[mi] = *reinterpret_cast<const bf16x8*>(
                &As[(mi * 16 + l15) * PKA + quad * 8]);
        #pragma unroll
        for (int ni = 0; ni < 8; ++ni)
            bfr[ni] = *reinterpret_cast<const bf16x8*>(
                &Bs[(wave * 128 + ni * 16 + l15) * PKA + quad * 8]);
        #pragma unroll
        for (int mi = 0; mi < 4; ++mi)
            #pragma unroll
            for (int ni = 0; ni < 8; ++ni)
                acc[mi][ni] = __builtin_amdgcn_mfma_f32_16x16x32_bf16(
                    afr[mi], bfr[ni], acc[mi][ni], 0, 0, 0);
    }

    // ---- epilogue: relu(u+g)*w0, reduce over n ----
    float rsum[16];
    #pragma unroll
    for (int i = 0; i < 16; ++i) rsum[i] = 0.f;
    #pragma unroll
    for (int ni = 0; ni < 8; ++ni) {
        const int n  = wave * 128 + ni * 16 + l15;   // D col = lane&15
        const float gv = g[(b << 9) + n];
        const float w0 = Wg0[n];
        #pragma unroll
        for (int mi = 0; mi < 4; ++mi)
            #pragma unroll
            for (int r = 0; r < 4; ++r) {            // D row = quad*4 + r
                float u = acc[mi][ni][r] + gv;
                u = fmaxf(u, 0.f);
                rsum[mi * 4 + r] += u * w0;
            }
    }
    // reduce across the 16 lanes that share the same rows (vary l15 = n)
    #pragma unroll
    for (int i = 0; i < 16; ++i) {
        float v = rsum[i];
        v += __shfl_xor(v, 1);
        v += __shfl_xor(v, 2);
        v += __shfl_xor(v, 4);
        v += __shfl_xor(v, 8);
        rsum[i] = v;
    }
    if (l15 == 0) {
        #pragma unroll
        for (int mi = 0; mi < 4; ++mi)
            #pragma unroll
            for (int r = 0; r < 4; ++r)
                sred[wave][mi * 16 + quad * 4 + r] = rsum[mi * 4 + r];
    }
    __syncthreads();
    if (t < 64) {
        const float sc = sred[0][t] + sred[1][t] + sred[2][t] + sred[3][t];
        const int grow = row0 + t;
        score[grow] = (mask[grow] == 0) ? -1e30f : sc;
    }
}

// ---------------------------------------------------------------------------
// K3: entmax bisection, one block (256 thr) per batch, 2 elems per thread.
// ---------------------------------------------------------------------------
__device__ __forceinline__ float block_sum(float v, float* red, int t) {
    v += __shfl_xor(v, 1);
    v += __shfl_xor(v, 2);
    v += __shfl_xor(v, 4);
    v += __shfl_xor(v, 8);
    v += __shfl_xor(v, 16);
    v += __shfl_xor(v, 32);
    __syncthreads();                 // protect red from previous use
    if ((t & 63) == 0) red[t >> 6] = v;
    __syncthreads();
    return red[0] + red[1] + red[2] + red[3];
}

__global__ __launch_bounds__(256) void k_entmax(const float* __restrict__ score,
                                                const float* __restrict__ alpha,
                                                float* __restrict__ p) {
    __shared__ float red[4];
    const int b = blockIdx.x;
    const int t = threadIdx.x;
    const float am1 = alpha[0] - 1.0f;
    const float inv = 1.0f / am1;
    const float x0 = score[(b << 9) + t] * am1;
    const float x1 = score[(b << 9) + 256 + t] * am1;

    // block max
    float m = fmaxf(x0, x1);
    m = fmaxf(m, __shfl_xor(m, 1));
    m = fmaxf(m, __shfl_xor(m, 2));
    m = fmaxf(m, __shfl_xor(m, 4));
    m = fmaxf(m, __shfl_xor(m, 8));
    m = fmaxf(m, __shfl_xor(m, 16));
    m = fmaxf(m, __shfl_xor(m, 32));
    if ((t & 63) == 0) red[t >> 6] = m;
    __syncthreads();
    m = fmaxf(fmaxf(red[0], red[1]), fmaxf(red[2], red[3]));

    float tau_lo = m - 1.0f;
    const float tau_hi = m - powf(1.0f / 512.0f, am1);
    float dm = tau_hi - tau_lo;

    const float f_lo = block_sum(powf(fmaxf(x0 - tau_lo, 0.f), inv) +
                                 powf(fmaxf(x1 - tau_lo, 0.f), inv), red, t) - 1.0f;
    for (int it = 0; it < 50; ++it) {
        dm *= 0.5f;
        const float tau_m = tau_lo + dm;
        const float f_m = block_sum(powf(fmaxf(x0 - tau_m, 0.f), inv) +
                                    powf(fmaxf(x1 - tau_m, 0.f), inv), red, t) - 1.0f;
        if (f_m * f_lo >= 0.f) tau_lo = tau_m;   // uniform branch (f_m identical per thread)
    }
    const float tau = tau_lo + 0.5f * dm;
    const float p0 = powf(fmaxf(x0 - tau, 0.f), inv);
    const float p1 = powf(fmaxf(x1 - tau, 0.f), inv);
    const float Z = block_sum(p0 + p1, red, t);
    p[(b << 9) + t]       = p0 / Z;
    p[(b << 9) + 256 + t] = p1 / Z;
}

// ---------------------------------------------------------------------------
// K4: attn[b][e] = sum_l p[b,l] * C[b,l,e]   (grid = B x 2 e-halves)
// ---------------------------------------------------------------------------
__global__ __launch_bounds__(256) void k_attn(const float* __restrict__ p,
                                              const float* __restrict__ C,
                                              float* __restrict__ attn) {
    const int b = blockIdx.x >> 1;
    const int e = ((blockIdx.x & 1) << 8) + threadIdx.x;
    const float* Cb = C + (size_t)b * 512 * 512;
    const float* pb = p + (b << 9);
    float acc = 0.f;
    #pragma unroll 4
    for (int l = 0; l < 512; ++l)
        acc += pb[l] * Cb[(size_t)l * 512 + e];
    attn[(b << 9) + e] = acc;
}

// ---------------------------------------------------------------------------
// K5: out[b][d] = sum_e attn[b][e] * X[b][e][d]   (grid = B x 2 e-halves, atomic)
// ---------------------------------------------------------------------------
__global__ __launch_bounds__(256) void k_out(const float* __restrict__ attn,
                                             const float* __restrict__ X,
                                             float* __restrict__ out) {
    const int b  = blockIdx.x;
    const int eh = blockIdx.y;
    const int d  = threadIdx.x;
    const float* Xb = X + (size_t)b * 512 * 256 + (size_t)eh * 256 * 256;
    const float* ab = attn + (b << 9) + (eh << 8);
    float acc = 0.f;
    #pragma unroll 4
    for (int e = 0; e < 256; ++e)
        acc += ab[e] * Xb[e * 256 + d];
    atomicAdd(&out[(b << 8) + d], acc);
}

// ---------------------------------------------------------------------------
extern "C" void kernel_launch(void* const* d_in, const int* in_sizes, int n_in,
                              void* d_out, int out_size, void* d_ws, size_t ws_size,
                              hipStream_t stream) {
    const float* C_target = (const float*)d_in[0];
    const float* C        = (const float*)d_in[1];
    const float* X        = (const float*)d_in[2];
    const float* alpha    = (const float*)d_in[3];
    const int*   mask     = (const int*)  d_in[4];
    const float* Wg1      = (const float*)d_in[5];
    const float* Wg2      = (const float*)d_in[6];
    const float* Wg0      = (const float*)d_in[7];
    const float* bias     = (const float*)d_in[8];
    float* out = (float*)d_out;

    char* ws = (char*)d_ws;
    bf16_t* wg1t = (bf16_t*)(ws);                    // 512 KB
    float*  g     = (float*)(ws + (512u << 10));     // 512 KB
    float*  score = (float*)(ws + (1024u << 10));    // 512 KB
    float*  p     = (float*)(ws + (1536u << 10));    // 512 KB
    float*  attn  = (float*)(ws + (2048u << 10));    // 512 KB

    k_wg1t  <<<dim3(16, 16), dim3(32, 8), 0, stream>>>(Wg1, wg1t);
    k_gate  <<<256, 256, 0, stream>>>(C_target, Wg2, bias, g);
    k_score <<<2048, 256, 0, stream>>>(C, wg1t, g, Wg0, mask, score);
    k_entmax<<<256, 256, 0, stream>>>(score, alpha, p);
    k_attn  <<<512, 256, 0, stream>>>(p, C, attn);
    hipMemsetAsync(d_out, 0, (size_t)out_size * sizeof(float), stream);
    k_out   <<<dim3(256, 2), 256, 0, stream>>>(attn, X, out);
}

// Round 2
// 595.494 us; speedup vs baseline: 1.1883x; 1.1883x over previous
//
#include <hip/hip_runtime.h>
#include <hip/hip_bf16.h>

typedef __bf16 bf16_t;
typedef bf16_t bf16x8 __attribute__((ext_vector_type(8)));
typedef float f32x4 __attribute__((ext_vector_type(4)));

// ---------------------------------------------------------------------------
// K0: Wg1 [k][e] fp32  ->  Wg1T [e][k] bf16  (32x32 LDS tile transpose)
// ---------------------------------------------------------------------------
__global__ void k_wg1t(const float* __restrict__ Wg1, bf16_t* __restrict__ Wg1T) {
    __shared__ float tile[32][33];
    const int k0 = blockIdx.x * 32;
    const int e0 = blockIdx.y * 32;
    const int tx = threadIdx.x;   // 0..31
    const int ty = threadIdx.y;   // 0..7
    #pragma unroll
    for (int i = 0; i < 32; i += 8)
        tile[ty + i][tx] = Wg1[(k0 + ty + i) * 512 + e0 + tx];
    __syncthreads();
    #pragma unroll
    for (int i = 0; i < 32; i += 8)
        Wg1T[(e0 + ty + i) * 512 + k0 + tx] = (bf16_t)tile[tx][ty + i];
}

// ---------------------------------------------------------------------------
// K1: g[b][e] = C_target[b,:] @ Wg2[:,e] + bias[e]   (grid = B x 2 e-halves)
// ---------------------------------------------------------------------------
__global__ __launch_bounds__(256) void k_gate(const float* __restrict__ Ct,
                                              const float* __restrict__ Wg2,
                                              const float* __restrict__ bias,
                                              float* __restrict__ g) {
    __shared__ float q[512];
    const int b = blockIdx.x;
    const int t = threadIdx.x;
    q[t]       = Ct[b * 512 + t];
    q[t + 256] = Ct[b * 512 + t + 256];
    __syncthreads();
    const int e = (blockIdx.y << 8) + t;
    float acc = bias[e];
    #pragma unroll 8
    for (int k = 0; k < 512; ++k)
        acc = fmaf(q[k], Wg2[k * 512 + e], acc);
    g[b * 512 + e] = acc;
}

// ---------------------------------------------------------------------------
// K2: big GEMM + fused relu/w0 reduction epilogue.
//   score[r] = sum_e relu( (C[r,:] @ Wg1)[e] + g[b,e] ) * w0[e],  masked.
// Block: 256 thr / 4 waves. Tile M=64 x N=512(full), K chunks of 32.
// LDS stride 32 (UNPADDED): start bank = (16*l15 + 4*quad) % 32 is exactly
// uniform (8 slots/bank) for the b128 fragment reads -> conflict-free.
// B staged with global_load_lds width 16 (dest is lane-contiguous x16B).
// ---------------------------------------------------------------------------
__global__ __launch_bounds__(256, 2) void k_score(const float* __restrict__ C,
                                                  const bf16_t* __restrict__ Wg1T,
                                                  const float* __restrict__ g,
                                                  const float* __restrict__ Wg0,
                                                  const int* __restrict__ mask,
                                                  float* __restrict__ score) {
    __shared__ bf16_t As[64 * 32];      //  4 KB
    __shared__ bf16_t Bs[512 * 32];     // 32 KB
    __shared__ float  sred[4][64];      //  1 KB

    const int t    = threadIdx.x;
    const int lane = t & 63;
    const int wave = t >> 6;
    const int quad = lane >> 4;
    const int l15  = lane & 15;
    const int row0 = blockIdx.x * 64;   // 2048 blocks
    const int b    = row0 >> 9;         // one batch per block

    f32x4 acc[4][8] = {};               // [mi][ni]

    for (int kc = 0; kc < 512; kc += 32) {
        __syncthreads();
        // ---- stage B: 512 n x 32 k of Wg1T, async DMA straight to LDS ----
        #pragma unroll
        for (int i = 0; i < 8; ++i) {
            const int f  = i * 256 + t;        // 0..2047 16-B slots
            const int r  = f >> 2;
            const int c8 = (f & 3) << 3;
            __builtin_amdgcn_global_load_lds(
                (const __attribute__((address_space(1))) void*)(Wg1T + r * 512 + kc + c8),
                (__attribute__((address_space(3))) void*)(Bs + f * 8), 16, 0, 0);
        }
        // ---- stage A: 64 rows x 32 k, fp32 -> bf16 (overlaps the B DMA) ----
        #pragma unroll
        for (int i = 0; i < 2; ++i) {
            const int f  = i * 256 + t;        // 0..511 float4 slots
            const int r  = f >> 3;
            const int c4 = (f & 7) << 2;
            const float4 v = *reinterpret_cast<const float4*>(
                &C[(size_t)(row0 + r) * 512 + kc + c4]);
            union { bf16_t h[4]; uint2 u; } pk;
            pk.h[0] = (bf16_t)v.x; pk.h[1] = (bf16_t)v.y;
            pk.h[2] = (bf16_t)v.z; pk.h[3] = (bf16_t)v.w;
            *reinterpret_cast<uint2*>(&As[r * 32 + c4]) = pk.u;
        }
        __syncthreads();
        // ---- fragments + 32 MFMA ----
        bf16x8 afr[4], bfr[8];
        #pragma unroll
        for (int mi = 0; mi < 4; ++mi)
            afr[mi] = *reinterpret_cast<const bf16x8*>(
                &As[(mi * 16 + l15) * 32 + quad * 8]);
        #pragma unroll
        for (int ni = 0; ni < 8; ++ni)
            bfr[ni] = *reinterpret_cast<const bf16x8*>(
                &Bs[(wave * 128 + ni * 16 + l15) * 32 + quad * 8]);
        #pragma unroll
        for (int mi = 0; mi < 4; ++mi)
            #pragma unroll
            for (int ni = 0; ni < 8; ++ni)
                acc[mi][ni] = __builtin_amdgcn_mfma_f32_16x16x32_bf16(
                    afr[mi], bfr[ni], acc[mi][ni], 0, 0, 0);
    }

    // ---- epilogue: relu(u+g)*w0, reduce over n ----
    float rsum[16];
    #pragma unroll
    for (int i = 0; i < 16; ++i) rsum[i] = 0.f;
    #pragma unroll
    for (int ni = 0; ni < 8; ++ni) {
        const int n  = wave * 128 + ni * 16 + l15;   // D col = lane&15
        const float gv = g[(b << 9) + n];
        const float w0 = Wg0[n];
        #pragma unroll
        for (int mi = 0; mi < 4; ++mi)
            #pragma unroll
            for (int r = 0; r < 4; ++r) {            // D row = quad*4 + r
                float u = fmaxf(acc[mi][ni][r] + gv, 0.f);
                rsum[mi * 4 + r] = fmaf(u, w0, rsum[mi * 4 + r]);
            }
    }
    #pragma unroll
    for (int i = 0; i < 16; ++i) {
        float v = rsum[i];
        v += __shfl_xor(v, 1);
        v += __shfl_xor(v, 2);
        v += __shfl_xor(v, 4);
        v += __shfl_xor(v, 8);
        rsum[i] = v;
    }
    if (l15 == 0) {
        #pragma unroll
        for (int mi = 0; mi < 4; ++mi)
            #pragma unroll
            for (int r = 0; r < 4; ++r)
                sred[wave][mi * 16 + quad * 4 + r] = rsum[mi * 4 + r];
    }
    __syncthreads();
    if (t < 64) {
        const float sc = sred[0][t] + sred[1][t] + sred[2][t] + sred[3][t];
        const int grow = row0 + t;
        score[grow] = (mask[grow] == 0) ? -1e30f : sc;
    }
}

// ---------------------------------------------------------------------------
// K3: entmax bisection — ONE WAVE PER BATCH, no barriers, x^2 fast path.
// grid 64 blocks x 256 thr (4 waves = 4 batches per block).
// ---------------------------------------------------------------------------
__global__ __launch_bounds__(256) void k_entmax(const float* __restrict__ score,
                                                const float* __restrict__ alpha,
                                                float* __restrict__ p) {
    const int wave = threadIdx.x >> 6;
    const int lane = threadIdx.x & 63;
    const int b    = (blockIdx.x << 2) + wave;
    const float am1 = alpha[0] - 1.0f;
    const float inv = 1.0f / am1;
    const bool  sq  = fabsf(inv - 2.0f) < 1e-6f;   // alpha==1.5 -> u*u

    const float* sb = score + (b << 9);
    float x[8];
    {
        const float4 v0 = *reinterpret_cast<const float4*>(sb + lane * 8);
        const float4 v1 = *reinterpret_cast<const float4*>(sb + lane * 8 + 4);
        x[0] = v0.x * am1; x[1] = v0.y * am1; x[2] = v0.z * am1; x[3] = v0.w * am1;
        x[4] = v1.x * am1; x[5] = v1.y * am1; x[6] = v1.z * am1; x[7] = v1.w * am1;
    }
    float m = x[0];
    #pragma unroll
    for (int j = 1; j < 8; ++j) m = fmaxf(m, x[j]);
    #pragma unroll
    for (int s = 1; s < 64; s <<= 1) m = fmaxf(m, __shfl_xor(m, s));

    float tau_lo = m - 1.0f;
    float dm = (m - powf(1.0f / 512.0f, am1)) - tau_lo;

    // f(tau_lo): butterfly sum is bitwise-identical on every lane -> uniform
    float f_lo;
    {
        float s = 0.f;
        #pragma unroll
        for (int j = 0; j < 8; ++j) {
            const float u = fmaxf(x[j] - tau_lo, 0.f);
            s += sq ? u * u : powf(u, inv);
        }
        #pragma unroll
        for (int sh = 1; sh < 64; sh <<= 1) s += __shfl_xor(s, sh);
        f_lo = s - 1.0f;
    }
    for (int it = 0; it < 50; ++it) {
        dm *= 0.5f;
        const float tau_m = tau_lo + dm;
        float s = 0.f;
        #pragma unroll
        for (int j = 0; j < 8; ++j) {
            const float u = fmaxf(x[j] - tau_m, 0.f);
            s += sq ? u * u : powf(u, inv);
        }
        #pragma unroll
        for (int sh = 1; sh < 64; sh <<= 1) s += __shfl_xor(s, sh);
        if ((s - 1.0f) * f_lo >= 0.f) tau_lo = tau_m;
    }
    const float tau = tau_lo + 0.5f * dm;
    float pj[8];
    float Z = 0.f;
    #pragma unroll
    for (int j = 0; j < 8; ++j) {
        const float u = fmaxf(x[j] - tau, 0.f);
        pj[j] = sq ? u * u : powf(u, inv);
        Z += pj[j];
    }
    #pragma unroll
    for (int sh = 1; sh < 64; sh <<= 1) Z += __shfl_xor(Z, sh);
    const float rz = 1.0f / Z;
    float4 o0, o1;
    o0.x = pj[0] * rz; o0.y = pj[1] * rz; o0.z = pj[2] * rz; o0.w = pj[3] * rz;
    o1.x = pj[4] * rz; o1.y = pj[5] * rz; o1.z = pj[6] * rz; o1.w = pj[7] * rz;
    *reinterpret_cast<float4*>(p + (b << 9) + lane * 8)     = o0;
    *reinterpret_cast<float4*>(p + (b << 9) + lane * 8 + 4) = o1;
}

// ---------------------------------------------------------------------------
// K4: partial attn over l-chunks: part[(b*4+ch)][e] = sum_{l in chunk} p*C
// grid (256, 4). Uniform skip of p==0 rows (masked half guaranteed zero).
// ---------------------------------------------------------------------------
__global__ __launch_bounds__(256) void k_attn(const float* __restrict__ p,
                                              const float* __restrict__ C,
                                              float* __restrict__ part) {
    __shared__ float pv_s[128];
    const int b  = blockIdx.x;
    const int ch = blockIdx.y;
    const int t  = threadIdx.x;
    const float* Cb = C + (size_t)b * 512 * 512 + (size_t)ch * 128 * 512;
    const float* pb = p + (b << 9) + (ch << 7);
    if (t < 128) pv_s[t] = pb[t];
    __syncthreads();
    float a0 = 0.f, a1 = 0.f;
    for (int l = 0; l < 128; ++l) {
        const float pv = pv_s[l];
        if (pv != 0.f) {                       // uniform branch (same pv blockwide)
            a0 = fmaf(pv, Cb[(size_t)l * 512 + t], a0);
            a1 = fmaf(pv, Cb[(size_t)l * 512 + t + 256], a1);
        }
    }
    float* pp = part + (size_t)((b << 2) + ch) * 512;
    pp[t]       = a0;
    pp[t + 256] = a1;
}

// ---------------------------------------------------------------------------
// K5: out[b][d] += sum_{e in chunk} attn[b][e] * X[b][e][d], attn = sum of 4
// partials (combined in LDS). grid (256, 4 e-chunks), atomicAdd epilogue.
// ---------------------------------------------------------------------------
__global__ __launch_bounds__(256) void k_out(const float* __restrict__ part,
                                             const float* __restrict__ X,
                                             float* __restrict__ out) {
    __shared__ float as_[128];
    const int b  = blockIdx.x;
    const int ec = blockIdx.y;
    const int t  = threadIdx.x;
    if (t < 128) {
        const int e = (ec << 7) + t;
        const float* pp = part + (size_t)(b << 2) * 512;
        as_[t] = pp[e] + pp[512 + e] + pp[1024 + e] + pp[1536 + e];
    }
    __syncthreads();
    const float* Xb = X + (size_t)b * 512 * 256 + (size_t)(ec << 7) * 256;
    float acc = 0.f;
    #pragma unroll 4
    for (int e = 0; e < 128; ++e)
        acc = fmaf(as_[e], Xb[e * 256 + t], acc);
    atomicAdd(&out[(b << 8) + t], acc);
}

// ---------------------------------------------------------------------------
extern "C" void kernel_launch(void* const* d_in, const int* in_sizes, int n_in,
                              void* d_out, int out_size, void* d_ws, size_t ws_size,
                              hipStream_t stream) {
    const float* C_target = (const float*)d_in[0];
    const float* C        = (const float*)d_in[1];
    const float* X        = (const float*)d_in[2];
    const float* alpha    = (const float*)d_in[3];
    const int*   mask     = (const int*)  d_in[4];
    const float* Wg1      = (const float*)d_in[5];
    const float* Wg2      = (const float*)d_in[6];
    const float* Wg0      = (const float*)d_in[7];
    const float* bias     = (const float*)d_in[8];
    float* out = (float*)d_out;

    char* ws = (char*)d_ws;
    bf16_t* wg1t  = (bf16_t*)(ws);                   // 512 KB
    float*  g     = (float*)(ws + (512u << 10));     // 512 KB
    float*  score = (float*)(ws + (1024u << 10));    // 512 KB
    float*  p     = (float*)(ws + (1536u << 10));    // 512 KB
    float*  part  = (float*)(ws + (2048u << 10));    // 2 MB

    k_wg1t  <<<dim3(16, 16), dim3(32, 8), 0, stream>>>(Wg1, wg1t);
    k_gate  <<<dim3(256, 2), 256, 0, stream>>>(C_target, Wg2, bias, g);
    k_score <<<2048, 256, 0, stream>>>(C, wg1t, g, Wg0, mask, score);
    k_entmax<<<64, 256, 0, stream>>>(score, alpha, p);
    k_attn  <<<dim3(256, 4), 256, 0, stream>>>(p, C, part);
    hipMemsetAsync(d_out, 0, (size_t)out_size * sizeof(float), stream);
    k_out   <<<dim3(256, 4), 256, 0, stream>>>(part, X, out);
}